// Round 6
// baseline (304.963 us; speedup 1.0000x reference)
//
#include <hip/hip_runtime.h>

// NMS3D: x (4,2,64,256,256) f32, 3x3x3 neighborhood-max excluding center,
// edge padding == index clamping.
//
// R10 = R9 with ONE variable changed: resident waves/CU 12 -> ~22.
// R9 post-mortem: VGPR=80 (6 waves/SIMD allowed) but grid 768 gave only
// 3 blocks/CU -> Occupancy 28%. The untested matrix cell across R4-R9 is
// {high wave count x fully independent waves} -- the regime streaming
// benchmarks run in. DC 11->6 (11 z-chunks), grid 768 -> 1408 blocks
// (5.5 blocks/CU x 4 waves ~ 22 waves/CU), launch_bounds(256,6) (VGPR
// cap 85 >= measured 80). Everything else byte-identical to R9:
// register-only PF=3 pipeline, no LDS, no barriers, 4 rows/wave,
// volume==XCD decode.

constexpr int D_  = 64;
constexpr int H_  = 256;
constexpr int W_  = 256;
constexpr int HW_ = H_ * W_;
constexpr int DC  = 6;         // z-chunk size (11 chunks; last emits 4)
constexpr int NCK = 11;        // ceil(64/6)
constexpr int S   = DC + 2;    // 8 slices touched per chunk
constexpr int PF  = 3;         // register pipeline depth (slices)

__device__ __forceinline__ float f3(float a, float b, float c) {
    return fmaxf(fmaxf(a, b), c);
}

__global__ __launch_bounds__(256, 6)
void nms3d(const float* __restrict__ x, float* __restrict__ out)
{
    const int tx  = threadIdx.x;          // 0..63 lane
    const int ty  = threadIdx.y;          // 0..3 wave id
    const int bid = blockIdx.x;           // 0..1407
    const int n    = bid & 7;             // volume == XCD
    const int rest = bid >> 3;            // 0..175
    const int rg   = rest & 15;           // row-group (16 rows / block)
    const int ck   = rest >> 4;           // z-chunk 0..10
    const int z0   = ck * DC;
    const int R0   = (rg << 4) + (ty << 2);   // wave's first output row
    const int c    = tx << 2;

    const float* __restrict__ base  = x   + (size_t)n * D_ * HW_;
    float* __restrict__       obase = out + (size_t)n * D_ * HW_;

    // element offsets of the 6 staged rows (h-clamped once)
    const int ro0 = max(R0 - 1, 0) * W_ + c;
    const int ro1 = (R0    ) * W_ + c;
    const int ro2 = (R0 + 1) * W_ + c;
    const int ro3 = (R0 + 2) * W_ + c;
    const int ro4 = (R0 + 3) * W_ + c;
    const int ro5 = min(R0 + 4, H_ - 1) * W_ + c;

    float4 wA[6], wB[6], wC[6];
    // per-row rolling state: vm9p = vmax9[z-1]; m2 = max(vmax9[z-2],cross8[z-1])
    float4 vm9p[4], m2[4], vprev[4];

#define LOADSET(WSET, SLICE) do {                                      \
        const int zc_ = min(max(z0 - 1 + (SLICE), 0), D_ - 1);         \
        const float* sp_ = base + (size_t)zc_ * HW_;                   \
        WSET[0] = *(const float4*)(sp_ + ro0);                         \
        WSET[1] = *(const float4*)(sp_ + ro1);                         \
        WSET[2] = *(const float4*)(sp_ + ro2);                         \
        WSET[3] = *(const float4*)(sp_ + ro3);                         \
        WSET[4] = *(const float4*)(sp_ + ro4);                         \
        WSET[5] = *(const float4*)(sp_ + ro5);                         \
    } while (0)

    LOADSET(wA, 0);
    LOADSET(wB, 1);
    LOADSET(wC, 2);

#pragma unroll
    for (int r = 0; r < 4; ++r) {
        vm9p[r]  = make_float4(0.f, 0.f, 0.f, 0.f);
        m2[r]    = make_float4(0.f, 0.f, 0.f, 0.f);
        vprev[r] = make_float4(0.f, 0.f, 0.f, 0.f);
    }

    // One slice step: compute on WCUR (slice T), emit out[z0+T-2], update
    // state, then reuse WCUR's registers to issue loads for slice T+PF.
#define STEP(T, WCUR) do {                                             \
        const int zo_ = z0 + (T) - 2;                                  \
        _Pragma("unroll")                                              \
        for (int r = 0; r < 4; ++r) {                                  \
            const float4 up = WCUR[r], dn = WCUR[r + 2], b0 = WCUR[r + 1]; \
            float4 va;                                                 \
            va.x = fmaxf(up.x, dn.x); va.y = fmaxf(up.y, dn.y);        \
            va.z = fmaxf(up.z, dn.z); va.w = fmaxf(up.w, dn.w);        \
            float vaL = __shfl_up(va.w, 1);   if (tx == 0)  vaL = va.x; \
            float vaR = __shfl_down(va.x, 1); if (tx == 63) vaR = va.w; \
            float bL  = __shfl_up(b0.w, 1);   if (tx == 0)  bL  = b0.x; \
            float bR  = __shfl_down(b0.x, 1); if (tx == 63) bR  = b0.w; \
            float4 hv, nb, c8, cur;                                    \
            hv.x = f3(vaL, va.x, va.y);  hv.y = f3(va.x, va.y, va.z);  \
            hv.z = f3(va.y, va.z, va.w); hv.w = f3(va.z, va.w, vaR);   \
            nb.x = fmaxf(bL,  b0.y);  nb.y = fmaxf(b0.x, b0.z);        \
            nb.z = fmaxf(b0.y, b0.w); nb.w = fmaxf(b0.z, bR);          \
            c8.x = fmaxf(hv.x, nb.x); c8.y = fmaxf(hv.y, nb.y);        \
            c8.z = fmaxf(hv.z, nb.z); c8.w = fmaxf(hv.w, nb.w);        \
            cur.x = fmaxf(c8.x, b0.x); cur.y = fmaxf(c8.y, b0.y);      \
            cur.z = fmaxf(c8.z, b0.z); cur.w = fmaxf(c8.w, b0.w);      \
            if ((T) >= 2 && zo_ < D_) {                                \
                float4 mx, o;                                          \
                mx.x = fmaxf(m2[r].x, cur.x);                          \
                mx.y = fmaxf(m2[r].y, cur.y);                          \
                mx.z = fmaxf(m2[r].z, cur.z);                          \
                mx.w = fmaxf(m2[r].w, cur.w);                          \
                o.x = vprev[r].x > mx.x ? vprev[r].x : 0.0f;           \
                o.y = vprev[r].y > mx.y ? vprev[r].y : 0.0f;           \
                o.z = vprev[r].z > mx.z ? vprev[r].z : 0.0f;           \
                o.w = vprev[r].w > mx.w ? vprev[r].w : 0.0f;           \
                *(float4*)(obase + (size_t)zo_ * HW_ +                 \
                           (size_t)(R0 + r) * W_ + c) = o;             \
            }                                                          \
            float4 t2;                                                 \
            t2.x = fmaxf(vm9p[r].x, c8.x);                             \
            t2.y = fmaxf(vm9p[r].y, c8.y);                             \
            t2.z = fmaxf(vm9p[r].z, c8.z);                             \
            t2.w = fmaxf(vm9p[r].w, c8.w);                             \
            m2[r] = t2; vm9p[r] = cur; vprev[r] = b0;                  \
        }                                                              \
        if ((T) + PF < S) LOADSET(WCUR, (T) + PF);                     \
    } while (0)

    STEP(0, wA); STEP(1, wB); STEP(2, wC);
    STEP(3, wA); STEP(4, wB); STEP(5, wC);
    STEP(6, wA); STEP(7, wB);

#undef STEP
#undef LOADSET
}

extern "C" void kernel_launch(void* const* d_in, const int* in_sizes, int n_in,
                              void* d_out, int out_size, void* d_ws, size_t ws_size,
                              hipStream_t stream)
{
    const float* x = (const float*)d_in[0];
    float* out = (float*)d_out;
    dim3 block(64, 4, 1);                  // 4 independent waves; wave = 4 rows
    dim3 grid(8 * 16 * NCK, 1, 1);         // vol x rowgroup x zchunk = 1408
    nms3d<<<grid, block, 0, stream>>>(x, out);
}

// Round 7
// 234.523 us; speedup vs baseline: 1.3004x; 1.3004x over previous
//
#include <hip/hip_runtime.h>

// NMS3D: x (4,2,64,256,256) f32, 3x3x3 neighborhood-max excluding center,
// edge padding == index clamping.
//
// R11: the last unexplored cell = {independent waves} x {8-waves/EU bin}.
// R10 post-mortem: launch_bounds(256,6) is not a valid occupancy bin
// (waves/EU steps 8/4/2 at VGPR 64/128/256) -> compiler forced the 64-VGPR
// bin, spilled (WRITE 311MB incl. scratch), 151us. But its spill traffic
// proved HBM serves this pattern at 3.65+ TB/s -> the 2.5 TB/s plateau of
// R5-R9 is DEMAND-side. This kernel is engineered into the 64-VGPR bin:
//   - 1 output row/wave, 3 staged rows, PF=2 -> 2 sets x 3 float4 = 24 VGPR
//   - folded state m2/vm9p/vprev = 12 VGPR; total ~55 (launch_bounds(256,8))
//   - no LDS, no barriers, compiler-managed waitcnt
//   - grid 4096 (16 blocks/CU, 8 resident) -> 32 waves/CU, copy-ubench regime
// Validity checks next round: VGPR<=64, WRITE_SIZE==131072 KB (no spill).

constexpr int D_  = 64;
constexpr int H_  = 256;
constexpr int W_  = 256;
constexpr int HW_ = H_ * W_;
constexpr int DC  = 8;         // z-chunk size (8 chunks)
constexpr int S   = DC + 2;    // 10 slices touched per chunk

__device__ __forceinline__ float f3(float a, float b, float c) {
    return fmaxf(fmaxf(a, b), c);
}

__global__ __launch_bounds__(256, 8)
void nms3d(const float* __restrict__ x, float* __restrict__ out)
{
    const int tx  = threadIdx.x;          // 0..63 lane
    const int ty  = threadIdx.y;          // 0..3 wave id; wave = 1 output row
    const int bid = blockIdx.x;           // 0..4095
    const int n    = bid & 7;             // volume == XCD
    const int rest = bid >> 3;            // 0..511
    const int rg   = rest & 63;           // row-group (4 rows / block)
    const int ck   = rest >> 6;           // z-chunk 0..7
    const int z0   = ck * DC;
    const int h    = (rg << 2) + ty;      // wave's output row
    const int c    = tx << 2;

    const float* __restrict__ base  = x   + (size_t)n * D_ * HW_;
    float* __restrict__       obase = out + (size_t)n * D_ * HW_;

    // element offsets of the 3 staged rows (h-clamped once)
    const int ro0 = max(h - 1, 0) * W_ + c;
    const int ro1 = h * W_ + c;
    const int ro2 = min(h + 1, H_ - 1) * W_ + c;

    float4 aA, bA, dA, aB, bB, dB;       // two slice sets (PF=2)
    // folded rolling state: m2 = max(vmax9[z-2], cross8[z-1])
    float4 m2   = {0,0,0,0};
    float4 vm9p = {0,0,0,0};
    float4 vprev= {0,0,0,0};

#define LOADSET(A_, B_, D_R, SLICE) do {                               \
        const int zc_ = min(max(z0 - 1 + (SLICE), 0), 63);             \
        const float* sp_ = base + (size_t)zc_ * HW_;                   \
        A_  = *(const float4*)(sp_ + ro0);                             \
        B_  = *(const float4*)(sp_ + ro1);                             \
        D_R = *(const float4*)(sp_ + ro2);                             \
    } while (0)

    LOADSET(aA, bA, dA, 0);
    LOADSET(aB, bB, dB, 1);

    // STEP(T): compute slice zi = z0-1+T from (a0,b0,d0); emit out[z0+T-2]
    // for T>=2; update folded state; reload this set with slice T+2.
#define STEP(T, A_, B_, D_R) do {                                      \
        const float4 up = A_, b0 = B_, dn = D_R;                       \
        float4 va;                                                     \
        va.x = fmaxf(up.x, dn.x); va.y = fmaxf(up.y, dn.y);            \
        va.z = fmaxf(up.z, dn.z); va.w = fmaxf(up.w, dn.w);            \
        float vaL = __shfl_up(va.w, 1);   if (tx == 0)  vaL = va.x;    \
        float vaR = __shfl_down(va.x, 1); if (tx == 63) vaR = va.w;    \
        float bL  = __shfl_up(b0.w, 1);   if (tx == 0)  bL  = b0.x;    \
        float bR  = __shfl_down(b0.x, 1); if (tx == 63) bR  = b0.w;    \
        float4 hv, nb, c8, cur;                                        \
        hv.x = f3(vaL, va.x, va.y);  hv.y = f3(va.x, va.y, va.z);      \
        hv.z = f3(va.y, va.z, va.w); hv.w = f3(va.z, va.w, vaR);       \
        nb.x = fmaxf(bL,  b0.y);  nb.y = fmaxf(b0.x, b0.z);            \
        nb.z = fmaxf(b0.y, b0.w); nb.w = fmaxf(b0.z, bR);              \
        c8.x = fmaxf(hv.x, nb.x); c8.y = fmaxf(hv.y, nb.y);            \
        c8.z = fmaxf(hv.z, nb.z); c8.w = fmaxf(hv.w, nb.w);            \
        cur.x = fmaxf(c8.x, b0.x); cur.y = fmaxf(c8.y, b0.y);          \
        cur.z = fmaxf(c8.z, b0.z); cur.w = fmaxf(c8.w, b0.w);          \
        if ((T) >= 2) {                                                \
            const int zo_ = z0 + (T) - 2;                              \
            float4 mx, o;                                              \
            mx.x = fmaxf(m2.x, cur.x); mx.y = fmaxf(m2.y, cur.y);      \
            mx.z = fmaxf(m2.z, cur.z); mx.w = fmaxf(m2.w, cur.w);      \
            o.x = vprev.x > mx.x ? vprev.x : 0.0f;                     \
            o.y = vprev.y > mx.y ? vprev.y : 0.0f;                     \
            o.z = vprev.z > mx.z ? vprev.z : 0.0f;                     \
            o.w = vprev.w > mx.w ? vprev.w : 0.0f;                     \
            *(float4*)(obase + (size_t)zo_ * HW_ + ro1) = o;           \
        }                                                              \
        m2.x = fmaxf(vm9p.x, c8.x); m2.y = fmaxf(vm9p.y, c8.y);        \
        m2.z = fmaxf(vm9p.z, c8.z); m2.w = fmaxf(vm9p.w, c8.w);        \
        vm9p = cur; vprev = b0;                                        \
        if ((T) + 2 < S) LOADSET(A_, B_, D_R, (T) + 2);                \
    } while (0)

    STEP(0, aA, bA, dA); STEP(1, aB, bB, dB);
    STEP(2, aA, bA, dA); STEP(3, aB, bB, dB);
    STEP(4, aA, bA, dA); STEP(5, aB, bB, dB);
    STEP(6, aA, bA, dA); STEP(7, aB, bB, dB);
    STEP(8, aA, bA, dA); STEP(9, aB, bB, dB);

#undef STEP
#undef LOADSET
}

extern "C" void kernel_launch(void* const* d_in, const int* in_sizes, int n_in,
                              void* d_out, int out_size, void* d_ws, size_t ws_size,
                              hipStream_t stream)
{
    const float* x = (const float*)d_in[0];
    float* out = (float*)d_out;
    dim3 block(64, 4, 1);                  // 4 independent waves; wave = 1 row
    dim3 grid(8 * 64 * (D_ / DC), 1, 1);   // vol x rowgroup x zchunk = 4096
    nms3d<<<grid, block, 0, stream>>>(x, out);
}